// Round 12
// baseline (236.464 us; speedup 1.0000x reference)
//
#include <hip/hip_runtime.h>
#include <math.h>

#define NLEV 8
#define D_DIM 1024

struct TB  { float  t[8]; };   // fp32 z-space thresholds (fast path)
struct TBD { double t[8]; };   // fp64 z-space thresholds (repair path)

typedef __attribute__((ext_vector_type(8))) short bf16x8;  // 8 bf16 (4 VGPRs) — guide §3
typedef __attribute__((ext_vector_type(4))) float f32x4;   // 4 fp32 acc

// RNE float->bf16 (bits in low 16)
__device__ __forceinline__ unsigned bf16_rne_bits(float f) {
    const unsigned u = __float_as_uint(f);
    return (u + 0x7FFFu + ((u >> 16) & 1u)) >> 16;
}
__device__ __forceinline__ float bf16_bits_to_f(unsigned h) {
    return __uint_as_float(h << 16);
}

// ---- DPP rotate-reduce within 16-lane rows (prologue C1/C0 only) ----
template<int CTRL>
__device__ __forceinline__ float ror_add(float v) {
    int r = __builtin_amdgcn_update_dpp(0, __float_as_int(v), CTRL, 0xF, 0xF, true);
    return v + __int_as_float(r);
}
__device__ __forceinline__ float red16(float v) {
    v = ror_add<0x121>(v); v = ror_add<0x122>(v);
    v = ror_add<0x124>(v); v = ror_add<0x128>(v);
    return v;
}
__device__ __forceinline__ float wave_allreduce(float v) {
    v = red16(v);
    v += __shfl_xor(v, 16, 64);
    v += __shfl_xor(v, 32, 64);
    return v;
}

// ---- fp64 repair (R7's field-verified math; x reloaded, L2/L3-hot) ----
__device__ __forceinline__ void repair_row_reload(
        int row, const float* __restrict__ xg,
        const float* __restrict__ gg, const float* __restrict__ bg,
        const float* __restrict__ Wg, float* __restrict__ outg,
        const TBD& tbd, int lane)
{
    const float4* xb4 = (const float4*)(xg + (size_t)row * D_DIM);
    const float4 x0 = xb4[lane];
    const float4 x1 = xb4[64 + lane];
    const float4 x2 = xb4[128 + lane];
    const float4 x3 = xb4[192 + lane];

    double ds = 0.0, dsq = 0.0;
    #pragma unroll
    for (int j = 0; j < 4; ++j) {
        const float4 a = (j == 0) ? x0 : (j == 1) ? x1 : (j == 2) ? x2 : x3;
        const double v0 = (double)a.x, v1 = (double)a.y;
        const double v2 = (double)a.z, v3 = (double)a.w;
        ds += ((v0 + v1) + (v2 + v3));
        dsq = fma(v0, v0, dsq); dsq = fma(v1, v1, dsq);
        dsq = fma(v2, v2, dsq); dsq = fma(v3, v3, dsq);
    }
    #pragma unroll
    for (int off = 32; off >= 1; off >>= 1) {
        ds  += __shfl_xor(ds, off, 64);
        dsq += __shfl_xor(dsq, off, 64);
    }
    const double mean = ds * (1.0 / 1024.0);
    const double var  = dsq * (1.0 / 1024.0) - mean * mean;
    const double rstd = 1.0 / sqrt(var + 1e-5);

    double dacc[NLEV];
    #pragma unroll
    for (int n = 0; n < NLEV; ++n) dacc[n] = 0.0;
    #pragma unroll
    for (int j = 0; j < 4; ++j) {
        const int col = j * 256 + lane * 4;
        const float4 a = (j == 0) ? x0 : (j == 1) ? x1 : (j == 2) ? x2 : x3;
        const float4 g4 = *(const float4*)(gg + col);
        const float4 b4 = *(const float4*)(bg + col);
        const double y0 = fma(((double)a.x - mean) * rstd, (double)g4.x, (double)b4.x);
        const double y1 = fma(((double)a.y - mean) * rstd, (double)g4.y, (double)b4.y);
        const double y2 = fma(((double)a.z - mean) * rstd, (double)g4.z, (double)b4.z);
        const double y3 = fma(((double)a.w - mean) * rstd, (double)g4.w, (double)b4.w);
        #pragma unroll
        for (int n = 0; n < NLEV; ++n) {
            const float4 w4 = *(const float4*)(Wg + n * D_DIM + col);
            dacc[n] = fma(y0, (double)w4.x, dacc[n]);
            dacc[n] = fma(y1, (double)w4.y, dacc[n]);
            dacc[n] = fma(y2, (double)w4.z, dacc[n]);
            dacc[n] = fma(y3, (double)w4.w, dacc[n]);
        }
    }
    #pragma unroll
    for (int off = 32; off >= 1; off >>= 1) {
        #pragma unroll
        for (int n = 0; n < NLEV; ++n) dacc[n] += __shfl_xor(dacc[n], off, 64);
    }
    if (lane < NLEV) {
        double a0d = (lane & 4) ? dacc[4] : dacc[0];
        double a1d = (lane & 4) ? dacc[5] : dacc[1];
        double a2d = (lane & 4) ? dacc[6] : dacc[2];
        double a3d = (lane & 4) ? dacc[7] : dacc[3];
        double b0d = (lane & 2) ? a2d : a0d;
        double b1d = (lane & 2) ? a3d : a1d;
        const double z = (lane & 1) ? b1d : b0d;
        int c = 0;
        #pragma unroll
        for (int k = 0; k < 8; ++k) c += (z > tbd.t[k]) ? 1 : 0;
        outg[(size_t)row * NLEV + lane] = (float)(c - 4);
    }
}

// ---------------- MFMA paradigm: 16 rows/wave, bf16 Dekker-split GEMM ----------
// R20: 11 rounds of variants inside the one-row-per-wave VALU paradigm all land
// 75-90 us with no saturated pipe; the paradigm itself was the never-changed
// variable. New structure: wave owns a 16-row tile; K-loop of 32 steps of
// mfma_f32_16x16x32_bf16 with B = [Vh(8)|Vl(8)] (V = g*W, RNE bf16 split) and
// two A-chains (xh, xl) -> all 4 partial products -> worst-case |dz| <=
// sum|xv|*2^-16 ~ 3e-4 < 1e-3 flag threshold (fp64 repair net unchanged).
// Per-row cost collapses: 2 LDS reads/row (was 32), ~110 VALU/row (was ~300),
// reduce/epilogue amortized 16x. C/D layout per guide-verified m89:
// col=lane&15, row=(lane>>4)*4+reg. A assumed row=lane&15, k=(lane>>4)*8+e
// (standard CDNA pattern; absmax!=0 would indicate this is wrong).
// GATES: VGPR<=96, WRITE~1.05MB. Success: fused 78 -> 20-40 us, MfmaUtil>0.
__global__ __launch_bounds__(256) void fsq_mfma(
        const float* __restrict__ xg,
        const float* __restrict__ gg,
        const float* __restrict__ bg,
        const float* __restrict__ Wg,
        float* __restrict__ outg,
        int nrows, TB tb, TBD tbd)
{
    __shared__ __align__(16) short Bf[32 * 64 * 8];   // 32 KB B-fragments
    __shared__ float redc1[4][NLEV];
    __shared__ float redc0[4][NLEV];

    const int tid  = (int)threadIdx.x;
    const int lane = tid & 63;
    const int wv   = tid >> 6;            // 0..3

    // ---- C1 = sum(g*W), C0 = sum(b*W) block reduction (fp32, as before) ----
    {
        const int col = tid * 4;          // 256 threads x 4 = 1024
        const float4 g4 = *(const float4*)(gg + col);
        const float4 b4 = *(const float4*)(bg + col);
        float pc1[NLEV], pc0[NLEV];
        #pragma unroll
        for (int n = 0; n < NLEV; ++n) {
            const float4 w4 = *(const float4*)(Wg + n * D_DIM + col);
            pc1[n] = (g4.x * w4.x + g4.y * w4.y) + (g4.z * w4.z + g4.w * w4.w);
            pc0[n] = (b4.x * w4.x + b4.y * w4.y) + (b4.z * w4.z + b4.w * w4.w);
        }
        #pragma unroll
        for (int n = 0; n < NLEV; ++n) {
            pc1[n] = wave_allreduce(pc1[n]);
            pc0[n] = wave_allreduce(pc0[n]);
        }
        if (lane == 0) {
            #pragma unroll
            for (int n = 0; n < NLEV; ++n) { redc1[wv][n] = pc1[n]; redc0[wv][n] = pc0[n]; }
        }
    }

    // ---- build B-fragments in LDS: slot = kstep*64 + lane, 16 B each ----
    // B[k][col]: col<8 -> bf16hi(V[col][k]); col>=8 -> bf16lo(V[col-8][k]).
    // Fragment layout: lane ln holds col=ln&15, k = kstep*32 + (ln>>4)*8 + e.
    #pragma unroll 1
    for (int i = 0; i < 8; ++i) {
        const int slot = tid + i * 256;       // 0..2047
        const int ks   = slot >> 6;
        const int ln   = slot & 63;
        const int cn   = ln & 15;
        const int n    = cn & 7;
        const int k0   = ks * 32 + (ln >> 4) * 8;
        const float4 ga  = *(const float4*)(gg + k0);
        const float4 gb2 = *(const float4*)(gg + k0 + 4);
        const float4 wa  = *(const float4*)(Wg + n * D_DIM + k0);
        const float4 wb  = *(const float4*)(Wg + n * D_DIM + k0 + 4);
        float v[8] = { ga.x * wa.x,  ga.y * wa.y,  ga.z * wa.z,  ga.w * wa.w,
                       gb2.x * wb.x, gb2.y * wb.y, gb2.z * wb.z, gb2.w * wb.w };
        bf16x8 frag;
        if (cn < 8) {
            #pragma unroll
            for (int e = 0; e < 8; ++e) frag[e] = (short)bf16_rne_bits(v[e]);
        } else {
            #pragma unroll
            for (int e = 0; e < 8; ++e) {
                const unsigned hb = bf16_rne_bits(v[e]);
                frag[e] = (short)bf16_rne_bits(v[e] - bf16_bits_to_f(hb));
            }
        }
        *(bf16x8*)&Bf[slot * 8] = frag;
    }
    __syncthreads();

    const int nsel = lane & 7;
    const float C1sel = redc1[0][nsel] + redc1[1][nsel] + redc1[2][nsel] + redc1[3][nsel];
    const float C0sel = redc0[0][nsel] + redc0[1][nsel] + redc0[2][nsel] + redc0[3][nsel];

    // ---- K-loop: 16-row tile, 32 steps x 2 MFMA ----
    const int row0  = (int)blockIdx.x * 64 + wv * 16;
    const int myrow = row0 + (lane & 15);
    const int rowc  = (myrow < nrows) ? myrow : (nrows - 1);
    const float* xrow = xg + (size_t)rowc * D_DIM + (lane >> 4) * 8;

    f32x4 acc1 = {0.f, 0.f, 0.f, 0.f};
    f32x4 acc2 = {0.f, 0.f, 0.f, 0.f};
    float s = 0.f, sq = 0.f;

    for (int ks = 0; ks < 32; ++ks) {
        const float4 xa  = *(const float4*)(xrow + ks * 32);
        const float4 xb2 = *(const float4*)(xrow + ks * 32 + 4);
        s += ((xa.x + xa.y) + (xa.z + xa.w)) + ((xb2.x + xb2.y) + (xb2.z + xb2.w));
        sq = fmaf(xa.x, xa.x, sq);   sq = fmaf(xa.y, xa.y, sq);
        sq = fmaf(xa.z, xa.z, sq);   sq = fmaf(xa.w, xa.w, sq);
        sq = fmaf(xb2.x, xb2.x, sq); sq = fmaf(xb2.y, xb2.y, sq);
        sq = fmaf(xb2.z, xb2.z, sq); sq = fmaf(xb2.w, xb2.w, sq);

        const float xs0[8] = { xa.x, xa.y, xa.z, xa.w, xb2.x, xb2.y, xb2.z, xb2.w };
        bf16x8 xh, xl;
        #pragma unroll
        for (int e = 0; e < 8; ++e) {
            const unsigned hb = bf16_rne_bits(xs0[e]);
            xh[e] = (short)hb;
            xl[e] = (short)bf16_rne_bits(xs0[e] - bf16_bits_to_f(hb));
        }
        const bf16x8 bfr = *(const bf16x8*)&Bf[(ks * 64 + lane) * 8];
        acc1 = __builtin_amdgcn_mfma_f32_16x16x32_bf16(xh, bfr, acc1, 0, 0, 0);
        acc2 = __builtin_amdgcn_mfma_f32_16x16x32_bf16(xl, bfr, acc2, 0, 0, 0);
    }

    // s/sq: lanes {l, l+16, l+32, l+48} hold k-chunks of row lane&15
    s  += __shfl_xor(s, 16, 64);  s  += __shfl_xor(s, 32, 64);
    sq += __shfl_xor(sq, 16, 64); sq += __shfl_xor(sq, 32, 64);
    const float mean_me = s * (1.0f / 1024.0f);
    const float var_me  = sq * (1.0f / 1024.0f) - mean_me * mean_me;
    const float rstd_me = 1.0f / sqrtf(var_me + 1e-5f);

    // ---- epilogue: C/D layout col=lane&15, row=(lane>>4)*4+reg ----
    unsigned rmaskw = 0u;
    const int grp = lane >> 4;
    #pragma unroll
    for (int r = 0; r < 4; ++r) {
        const float t = acc1[r] + acc2[r];
        const float S = t + __shfl_xor(t, 8, 64);   // col n (+) col n+8 partials
        const int srcl = (grp << 2) | r;            // lane holding row grp*4+r stats
        const float mean_r = __shfl(mean_me, srcl, 64);
        const float rstd_r = __shfl(rstd_me, srcl, 64);
        const float z = rstd_r * (S - mean_r * C1sel) + C0sel;

        int cnt = 0; float mind = 1e30f;
        #pragma unroll
        for (int k = 0; k < 8; ++k) {
            cnt += (z > tb.t[k]) ? 1 : 0;
            mind = fminf(mind, fabsf(z - tb.t[k]));
        }
        const int orow = row0 + grp * 4 + r;
        const bool rok = (orow < nrows);
        if (((lane & 15) < 8) && rok)
            outg[(size_t)orow * NLEV + (lane & 7)] = (float)(cnt - 4);
        const bool fl = ((lane & 15) < 8) && rok && (mind < 1.0e-3f);
        const unsigned long long bal = __ballot(fl);
        #pragma unroll
        for (int g2 = 0; g2 < 4; ++g2)
            if ((bal >> (g2 * 16)) & 0xFFFFull) rmaskw |= 1u << (g2 * 4 + r);
    }

    // ---- deferred fp64 repairs (wave-uniform mask over the 16-row tile) ----
    while (rmaskw) {
        const int p = __builtin_ctz(rmaskw);
        rmaskw &= rmaskw - 1u;
        repair_row_reload(row0 + p, xg, gg, bg, Wg, outg, tbd, lane);
    }
}

extern "C" void kernel_launch(void* const* d_in, const int* in_sizes, int n_in,
                              void* d_out, int out_size, void* d_ws, size_t ws_size,
                              hipStream_t stream) {
    (void)n_in; (void)out_size; (void)d_ws; (void)ws_size;  // workspace UNUSED
    const float* regrs = (const float*)d_in[0];
    const float* ln_w  = (const float*)d_in[1];
    const float* ln_b  = (const float*)d_in[2];
    const float* W     = (const float*)d_in[3];
    float* out = (float*)d_out;

    const int nrows = in_sizes[0] / D_DIM;      // 32768
    const int nblocks = (nrows + 63) / 64;      // 64 rows/block (4 waves x 16) -> 512 blocks

    TB tb; TBD tbd;
    for (int k = 0; k < 8; ++k) {
        const double y = ((double)k - 3.5) / 3.996;
        tbd.t[k] = atanh(y);           // fp64 z-space rounding boundaries
        tb.t[k]  = (float)tbd.t[k];
    }

    fsq_mfma<<<nblocks, 256, 0, stream>>>(regrs, ln_w, ln_b, W, out, nrows, tb, tbd);
}